// Round 17
// baseline (101.458 us; speedup 1.0000x reference)
//
#include <hip/hip_runtime.h>
#include <hip/hip_bf16.h>
#include <stdint.h>

typedef __bf16 bf16_t;
typedef bf16_t bf16x8 __attribute__((ext_vector_type(8)));
typedef bf16_t bf16x4 __attribute__((ext_vector_type(4)));
typedef float  f32x4  __attribute__((ext_vector_type(4)));

#define B_DIM 4096
#define I_DIM 1024
#define H_DIM 1024
#define K_DIM 2048   // I + H
#define N_DIM 4096   // 4*H
#define NT    (K_DIM / 64)   // 32 K-tiles

// ---------------------------------------------------------------------------
// Merged prep (one launch):
//   blocks [0, 4096):      A-row b = [x_b | h_b] -> bf16, + mask[b]
//   blocks [4096, 8192):   Wcat chunk (gate-interleaved rows), 8 elems/thread
// ---------------------------------------------------------------------------
__global__ void prep_kernel(const float* __restrict__ x,
                            const float* __restrict__ h,
                            const float* __restrict__ W0, const float* __restrict__ W1,
                            const float* __restrict__ W2, const float* __restrict__ W3,
                            const float* __restrict__ V0, const float* __restrict__ V1,
                            const float* __restrict__ V2, const float* __restrict__ V3,
                            bf16_t* __restrict__ A,
                            bf16_t* __restrict__ Wc,
                            float* __restrict__ mask) {
    const int blk = blockIdx.x;
    const int t   = threadIdx.x;
    if (blk < B_DIM) {
        const int b = blk;
        float4 vx = *(const float4*)&x[(size_t)b * I_DIM + t * 4];
        bf16x4 ox;
        ox[0] = (bf16_t)vx.x; ox[1] = (bf16_t)vx.y; ox[2] = (bf16_t)vx.z; ox[3] = (bf16_t)vx.w;
        *(bf16x4*)&A[(size_t)b * K_DIM + t * 4] = ox;
        float s = vx.x * vx.x + vx.y * vx.y + vx.z * vx.z + vx.w * vx.w;

        float4 vh = *(const float4*)&h[(size_t)b * H_DIM + t * 4];
        bf16x4 oh;
        oh[0] = (bf16_t)vh.x; oh[1] = (bf16_t)vh.y; oh[2] = (bf16_t)vh.z; oh[3] = (bf16_t)vh.w;
        *(bf16x4*)&A[(size_t)b * K_DIM + I_DIM + t * 4] = oh;

        #pragma unroll
        for (int off = 32; off > 0; off >>= 1) s += __shfl_down(s, off);
        __shared__ float ws[4];
        if ((t & 63) == 0) ws[t >> 6] = s;
        __syncthreads();
        if (t == 0) {
            float tt = ws[0] + ws[1] + ws[2] + ws[3];
            mask[b] = (sqrtf(tt) > 0.001f) ? 1.f : 0.f;
        }
    } else {
        int idx = ((blk - B_DIM) * 256 + t) * 8;   // element in [4096][2048]
        int n = idx >> 11;
        int c = idx & 2047;
        int g = (n >> 4) & 3;
        int hr = ((n >> 6) << 4) + (n & 15);
        const float* src;
        if (c < I_DIM) {
            const float* Wg = (g == 0) ? W0 : (g == 1) ? W1 : (g == 2) ? W2 : W3;
            src = Wg + (size_t)hr * I_DIM + c;
        } else {
            const float* Vg = (g == 0) ? V0 : (g == 1) ? V1 : (g == 2) ? V2 : V3;
            src = Vg + (size_t)hr * H_DIM + (c - I_DIM);
        }
        float4 v0 = *(const float4*)src;
        float4 v1 = *(const float4*)(src + 4);
        bf16x8 o;
        o[0] = (bf16_t)v0.x; o[1] = (bf16_t)v0.y; o[2] = (bf16_t)v0.z; o[3] = (bf16_t)v0.w;
        o[4] = (bf16_t)v1.x; o[5] = (bf16_t)v1.y; o[6] = (bf16_t)v1.z; o[7] = (bf16_t)v1.w;
        *(bf16x8*)&Wc[idx] = o;
    }
}

// ---------------------------------------------------------------------------
// Fused GEMM + LSTM. 256x256 tile, BK=64, 8 waves (2M x 4N).
// NEW (R17): SINGLE-buffered 32 KiB+32 KiB LDS (64 KiB total) -> TWO blocks
// resident per CU (16 waves/CU, 4/SIMD; VGPR 120 <= 128 budget). Per-block
// stage-wait (vmcnt(0)) and barrier drains are hidden by the OTHER block's
// compute (m114 cross-block overlap) instead of the failed intra-block
// phase pipelining. 256^2 tiling keeps FETCH at ~84 MB (R14's 128^2 tiling
// doubled it). Protocol per K-tile: vmcnt(0); barrier; compute; barrier;
// stage(t+1). LDS [256][64] per matrix, XOR swizzle byte ^= ((row&7)<<4).
// Bias folded into epilogue.
// ---------------------------------------------------------------------------
__device__ __forceinline__ float sigf(float v) { return 1.f / (1.f + __expf(-v)); }
__device__ __forceinline__ float tanf_(float v) { return 2.f / (1.f + __expf(-2.f * v)) - 1.f; }

#define BARRIER()  asm volatile("s_barrier" ::: "memory")
#define WAIT_VM(n) asm volatile("s_waitcnt vmcnt(" #n ")" ::: "memory")
#define GLL(gptr, ldst) \
    __builtin_amdgcn_global_load_lds( \
        (const __attribute__((address_space(1))) void*)(gptr), \
        (__attribute__((address_space(3))) void*)(ldst), 16, 0, 0)

__global__ __launch_bounds__(512, 2) void gemm_lstm(
    const bf16_t* __restrict__ A,     // [4096][2048]
    const bf16_t* __restrict__ W,     // [4096][2048] gate-interleaved rows
    const float* __restrict__ c_prev, // [4096][1024]
    const float* __restrict__ mask,   // [4096]
    float* __restrict__ out,          // [3][4096][1024]
    const float* __restrict__ bW0, const float* __restrict__ bW1,
    const float* __restrict__ bW2, const float* __restrict__ bW3,
    const float* __restrict__ bV0, const float* __restrict__ bV1,
    const float* __restrict__ bV2, const float* __restrict__ bV3,
    const float* __restrict__ bg0, const float* __restrict__ bg1,
    const float* __restrict__ bg2, const float* __restrict__ bg3)
{
    __shared__ bf16_t smem[32768];    // 64 KiB: A [256][64] | W [256][64]

    const int tid  = threadIdx.x;
    const int lane = tid & 63;
    const int wave = tid >> 6;     // 0..7
    const int wm   = wave >> 2;    // 0..1
    const int wn   = wave & 3;     // 0..3
    const int frow = lane & 15;
    const int g    = lane >> 4;    // 0..3 (k-group of 8)

    // XCD-aware block swizzle (grid = 256, divisible by 8)
    int bid = blockIdx.x;
    int wg  = (bid & 7) * 32 + (bid >> 3);
    const int m0 = (wg >> 4) * 256;
    const int n0 = (wg & 15) * 256;

    // ds_read byte offsets within a [256][64] tile:
    //   byte = row*128 + ((kh*64 + g*16) ^ ((row&7)<<4));  kh1 = kh0 ^ 64
    const int vswz = (frow & 7) << 4;
    int aoffB[8], boffB[4];
    #pragma unroll
    for (int mi = 0; mi < 8; ++mi) {
        int row = wm * 128 + mi * 16 + frow;
        aoffB[mi] = row * 128 + ((g * 16) ^ vswz);
    }
    #pragma unroll
    for (int nj = 0; nj < 4; ++nj) {
        int row = wn * 64 + nj * 16 + frow;
        boffB[nj] = row * 128 + ((g * 16) ^ vswz);
    }

    // GLL source addressing: dest byte in tile d = p*8192 + tid*16 (linear),
    // logical l = d ^ (((d>>7)&7)<<4)  ->  row = p*64 + (tid>>3), col swizzled.
    const int r0 = tid >> 3;                                   // 0..63
    const int cE = (((tid & 7) * 16) ^ ((r0 & 7) << 4)) >> 1;  // col element
    const bf16_t* pA[4];
    const bf16_t* pW[4];
    #pragma unroll
    for (int p = 0; p < 4; ++p) {
        pA[p] = A + (size_t)(m0 + p * 64 + r0) * K_DIM + cE;
        pW[p] = W + (size_t)(n0 + p * 64 + r0) * K_DIM + cE;
    }
    // LDS dest bases (lane*16 added by HW): A bytes [0,32K), W bytes [32K,64K)
    char* const dBase = (char*)smem + wave * 1024;

    f32x4 acc[8][4] = {};

    // ---- Prologue: stage tile 0 ----
    #pragma unroll
    for (int p = 0; p < 4; ++p) GLL(pW[p], dBase + 32768 + p * 8192);
    #pragma unroll
    for (int p = 0; p < 4; ++p) GLL(pA[p], dBase + p * 8192);
    #pragma unroll
    for (int p = 0; p < 4; ++p) { pA[p] += 64; pW[p] += 64; }

    for (int t = 0; t < NT; ++t) {
        WAIT_VM(0);        // own 8 GLLs landed (other block computes meanwhile)
        BARRIER();         // all waves' GLLs landed
        const char* sA = (const char*)smem;
        const char* sW = sA + 32768;
        #pragma unroll
        for (int kh = 0; kh < 2; ++kh) {
            bf16x8 bfr[4], af[4];
            #pragma unroll
            for (int nj = 0; nj < 4; ++nj)
                bfr[nj] = *(const bf16x8*)(sW + (boffB[nj] ^ (kh * 64)));
            #pragma unroll
            for (int mi = 0; mi < 4; ++mi)
                af[mi] = *(const bf16x8*)(sA + (aoffB[mi] ^ (kh * 64)));
            __builtin_amdgcn_s_setprio(1);
            #pragma unroll
            for (int mi = 0; mi < 4; ++mi)
                #pragma unroll
                for (int nj = 0; nj < 4; ++nj)
                    acc[mi][nj] = __builtin_amdgcn_mfma_f32_16x16x32_bf16(
                        af[mi], bfr[nj], acc[mi][nj], 0, 0, 0);
            __builtin_amdgcn_s_setprio(0);
            #pragma unroll
            for (int mi = 0; mi < 4; ++mi)
                af[mi] = *(const bf16x8*)(sA + (aoffB[4 + mi] ^ (kh * 64)));
            __builtin_amdgcn_s_setprio(1);
            #pragma unroll
            for (int mi = 0; mi < 4; ++mi)
                #pragma unroll
                for (int nj = 0; nj < 4; ++nj)
                    acc[4 + mi][nj] = __builtin_amdgcn_mfma_f32_16x16x32_bf16(
                        af[mi], bfr[nj], acc[4 + mi][nj], 0, 0, 0);
            __builtin_amdgcn_s_setprio(0);
        }
        BARRIER();         // all waves done reading before overwrite
        if (t + 1 < NT) {
            #pragma unroll
            for (int p = 0; p < 4; ++p) GLL(pW[p], dBase + 32768 + p * 8192);
            #pragma unroll
            for (int p = 0; p < 4; ++p) GLL(pA[p], dBase + p * 8192);
            #pragma unroll
            for (int p = 0; p < 4; ++p) { pA[p] += 64; pW[p] += 64; }
        }
    }

    // ----- fused LSTM epilogue (lane's 4 n-frags = the 4 gates of one h) -----
    const int hb = (n0 >> 2) + wn * 16 + frow;   // h index for this lane
    float bv[4];
    bv[0] = bW0[hb] + bV0[hb] + bg0[hb];
    bv[1] = bW1[hb] + bV1[hb] + bg1[hb];
    bv[2] = bW2[hb] + bV2[hb] + bg2[hb];
    bv[3] = bW3[hb] + bV3[hb] + bg3[hb];
    const int BH = B_DIM * H_DIM;

    #pragma unroll
    for (int mi = 0; mi < 8; ++mi) {
        int bbase = m0 + wm * 128 + mi * 16 + g * 4;
        #pragma unroll
        for (int r = 0; r < 4; ++r) {
            int b = bbase + r;
            float mk = mask[b];
            float cp = c_prev[(size_t)b * H_DIM + hb];
            float fv = sigf(acc[mi][0][r] + bv[0]);
            float iv = sigf(acc[mi][1][r] + bv[1]);
            float ov = sigf(acc[mi][2][r] + bv[2]);
            float ct = tanf_(acc[mi][3][r] + bv[3]);
            float cn = fv * cp + iv * cp + mk * (iv * ct);
            float hn = ov * tanf_(cn);
            size_t o = (size_t)b * H_DIM + hb;
            out[o]          = hn;
            out[BH + o]     = cn;
            out[2 * BH + o] = ct;
        }
    }
}

// ---------------------------------------------------------------------------
// Launch
// ---------------------------------------------------------------------------
extern "C" void kernel_launch(void* const* d_in, const int* in_sizes, int n_in,
                              void* d_out, int out_size, void* d_ws, size_t ws_size,
                              hipStream_t stream) {
    const float* x      = (const float*)d_in[0];
    const float* h_prev = (const float*)d_in[1];
    const float* c_prev = (const float*)d_in[2];
    const float* Wf = (const float*)d_in[4],  *bWf = (const float*)d_in[5];
    const float* Vf = (const float*)d_in[6],  *bVf = (const float*)d_in[7];
    const float* Wi = (const float*)d_in[8],  *bWi = (const float*)d_in[9];
    const float* Vi = (const float*)d_in[10], *bVi = (const float*)d_in[11];
    const float* Wo = (const float*)d_in[12], *bWo = (const float*)d_in[13];
    const float* Vo = (const float*)d_in[14], *bVo = (const float*)d_in[15];
    const float* Wcg = (const float*)d_in[16], *bWc = (const float*)d_in[17];
    const float* Vc = (const float*)d_in[18], *bVc = (const float*)d_in[19];
    const float* bf = (const float*)d_in[20];
    const float* bi = (const float*)d_in[21];
    const float* bo = (const float*)d_in[22];
    const float* bc = (const float*)d_in[23];

    uint8_t* ws = (uint8_t*)d_ws;
    bf16_t* Abuf  = (bf16_t*)ws;                                   // 16 MiB
    bf16_t* Wbuf  = (bf16_t*)(ws + (size_t)16 * 1024 * 1024);      // 16 MiB
    float*  maskb = (float*)(ws + (size_t)32 * 1024 * 1024);       // 16 KiB

    prep_kernel<<<2 * B_DIM, 256, 0, stream>>>(
        x, h_prev, Wf, Wi, Wo, Wcg, Vf, Vi, Vo, Vc, Abuf, Wbuf, maskb);

    gemm_lstm<<<256, 512, 0, stream>>>(Abuf, Wbuf, c_prev, maskb,
                                       (float*)d_out,
                                       bWf, bWi, bWo, bWc,
                                       bVf, bVi, bVo, bVc,
                                       bf, bi, bo, bc);
}

// Round 18
// 83.365 us; speedup vs baseline: 1.2170x; 1.2170x over previous
//
#include <hip/hip_runtime.h>
#include <hip/hip_bf16.h>
#include <stdint.h>

typedef __bf16 bf16_t;
typedef bf16_t bf16x8 __attribute__((ext_vector_type(8)));
typedef bf16_t bf16x4 __attribute__((ext_vector_type(4)));
typedef float  f32x4  __attribute__((ext_vector_type(4)));

#define B_DIM 4096
#define I_DIM 1024
#define H_DIM 1024
#define K_DIM 2048   // I + H
#define N_DIM 4096   // 4*H
#define NT    (K_DIM / 64)   // 32 K-tiles

// ---------------------------------------------------------------------------
// Merged prep (one launch):
//   blocks [0, 4096):      A-row b = [x_b | h_b] -> bf16, + mask[b]
//   blocks [4096, 8192):   Wcat chunk (gate-interleaved rows), 8 elems/thread
// ---------------------------------------------------------------------------
__global__ void prep_kernel(const float* __restrict__ x,
                            const float* __restrict__ h,
                            const float* __restrict__ W0, const float* __restrict__ W1,
                            const float* __restrict__ W2, const float* __restrict__ W3,
                            const float* __restrict__ V0, const float* __restrict__ V1,
                            const float* __restrict__ V2, const float* __restrict__ V3,
                            bf16_t* __restrict__ A,
                            bf16_t* __restrict__ Wc,
                            float* __restrict__ mask) {
    const int blk = blockIdx.x;
    const int t   = threadIdx.x;
    if (blk < B_DIM) {
        const int b = blk;
        float4 vx = *(const float4*)&x[(size_t)b * I_DIM + t * 4];
        bf16x4 ox;
        ox[0] = (bf16_t)vx.x; ox[1] = (bf16_t)vx.y; ox[2] = (bf16_t)vx.z; ox[3] = (bf16_t)vx.w;
        *(bf16x4*)&A[(size_t)b * K_DIM + t * 4] = ox;
        float s = vx.x * vx.x + vx.y * vx.y + vx.z * vx.z + vx.w * vx.w;

        float4 vh = *(const float4*)&h[(size_t)b * H_DIM + t * 4];
        bf16x4 oh;
        oh[0] = (bf16_t)vh.x; oh[1] = (bf16_t)vh.y; oh[2] = (bf16_t)vh.z; oh[3] = (bf16_t)vh.w;
        *(bf16x4*)&A[(size_t)b * K_DIM + I_DIM + t * 4] = oh;

        #pragma unroll
        for (int off = 32; off > 0; off >>= 1) s += __shfl_down(s, off);
        __shared__ float ws[4];
        if ((t & 63) == 0) ws[t >> 6] = s;
        __syncthreads();
        if (t == 0) {
            float tt = ws[0] + ws[1] + ws[2] + ws[3];
            mask[b] = (sqrtf(tt) > 0.001f) ? 1.f : 0.f;
        }
    } else {
        int idx = ((blk - B_DIM) * 256 + t) * 8;   // element in [4096][2048]
        int n = idx >> 11;
        int c = idx & 2047;
        int g = (n >> 4) & 3;
        int hr = ((n >> 6) << 4) + (n & 15);
        const float* src;
        if (c < I_DIM) {
            const float* Wg = (g == 0) ? W0 : (g == 1) ? W1 : (g == 2) ? W2 : W3;
            src = Wg + (size_t)hr * I_DIM + c;
        } else {
            const float* Vg = (g == 0) ? V0 : (g == 1) ? V1 : (g == 2) ? V2 : V3;
            src = Vg + (size_t)hr * H_DIM + (c - I_DIM);
        }
        float4 v0 = *(const float4*)src;
        float4 v1 = *(const float4*)(src + 4);
        bf16x8 o;
        o[0] = (bf16_t)v0.x; o[1] = (bf16_t)v0.y; o[2] = (bf16_t)v0.z; o[3] = (bf16_t)v0.w;
        o[4] = (bf16_t)v1.x; o[5] = (bf16_t)v1.y; o[6] = (bf16_t)v1.z; o[7] = (bf16_t)v1.w;
        *(bf16x8*)&Wc[idx] = o;
    }
}

// ---------------------------------------------------------------------------
// Fused GEMM + LSTM. 256x256 tile, BK=64, 8 waves (2M x 4N), dbuf LDS 128 KiB.
// R4/R12/R13/R16 proven-fastest schedule: 2 barriers + 2 counted vmcnt per
// K-tile, W staged at P1, A staged at P2 (order p0,p2,p1,p3), never drained
// to 0. LDS [256][64] per matrix, XOR swizzle byte ^= ((row&7)<<4).
// Bias (bW+bV+b per gate) folded into the epilogue. TERMINAL CONFIGURATION:
// 12 structural variants bracket this at 77-98 us GEMM; this one is the
// reproducible optimum (~78 us GEMM ~= 880 TF, the plain-HIP coarse-structure
// ceiling). Failed escapes (each with diagnosed mechanism): 3x 8-phase ports
// (lockstep/pin), B-streaming (TA gather flood), 128x128/wave + tail-peel
// (VGPR spill), m97-TLP at 128^2 (2x L2 refetch), 1-buf 2-block (exposed
// stage latency). fp8/MX closed by accuracy (absmax threshold 0.1775).
// ---------------------------------------------------------------------------
__device__ __forceinline__ float sigf(float v) { return 1.f / (1.f + __expf(-v)); }
__device__ __forceinline__ float tanf_(float v) { return 2.f / (1.f + __expf(-2.f * v)) - 1.f; }

#define BARRIER()  asm volatile("s_barrier" ::: "memory")
#define WAIT_VM(n) asm volatile("s_waitcnt vmcnt(" #n ")" ::: "memory")
#define GLL(gptr, ldst) \
    __builtin_amdgcn_global_load_lds( \
        (const __attribute__((address_space(1))) void*)(gptr), \
        (__attribute__((address_space(3))) void*)(ldst), 16, 0, 0)

__global__ __launch_bounds__(512, 2) void gemm_lstm(
    const bf16_t* __restrict__ A,     // [4096][2048]
    const bf16_t* __restrict__ W,     // [4096][2048] gate-interleaved rows
    const float* __restrict__ c_prev, // [4096][1024]
    const float* __restrict__ mask,   // [4096]
    float* __restrict__ out,          // [3][4096][1024]
    const float* __restrict__ bW0, const float* __restrict__ bW1,
    const float* __restrict__ bW2, const float* __restrict__ bW3,
    const float* __restrict__ bV0, const float* __restrict__ bV1,
    const float* __restrict__ bV2, const float* __restrict__ bV3,
    const float* __restrict__ bg0, const float* __restrict__ bg1,
    const float* __restrict__ bg2, const float* __restrict__ bg3)
{
    __shared__ bf16_t smem[65536];    // 128 KiB: [buf2][A 32KB | W 32KB]

    const int tid  = threadIdx.x;
    const int lane = tid & 63;
    const int wave = tid >> 6;     // 0..7
    const int wm   = wave >> 2;    // 0..1
    const int wn   = wave & 3;     // 0..3
    const int frow = lane & 15;
    const int g    = lane >> 4;    // 0..3 (k-group of 8)

    // XCD-aware block swizzle (grid = 256, divisible by 8)
    int bid = blockIdx.x;
    int wg  = (bid & 7) * 32 + (bid >> 3);
    const int m0 = (wg >> 4) * 256;
    const int n0 = (wg & 15) * 256;

    // ds_read byte offsets within a [256][64] tile:
    //   byte = row*128 + ((kh*64 + g*16) ^ ((row&7)<<4));  kh1 = kh0 ^ 64
    const int vswz = (frow & 7) << 4;
    int aoffB[8], boffB[4];
    #pragma unroll
    for (int mi = 0; mi < 8; ++mi) {
        int row = wm * 128 + mi * 16 + frow;
        aoffB[mi] = row * 128 + ((g * 16) ^ vswz);
    }
    #pragma unroll
    for (int nj = 0; nj < 4; ++nj) {
        int row = wn * 64 + nj * 16 + frow;
        boffB[nj] = row * 128 + ((g * 16) ^ vswz);
    }

    // GLL source addressing: dest byte in tile d = p*8192 + tid*16 (linear),
    // logical l = d ^ (((d>>7)&7)<<4)  ->  row = p*64 + (tid>>3), col swizzled.
    const int r0 = tid >> 3;                                   // 0..63
    const int cE = (((tid & 7) * 16) ^ ((r0 & 7) << 4)) >> 1;  // col element
    const bf16_t* pA[4];
    const bf16_t* pW[4];
    #pragma unroll
    for (int p = 0; p < 4; ++p) {
        pA[p] = A + (size_t)(m0 + p * 64 + r0) * K_DIM + cE;
        pW[p] = W + (size_t)(n0 + p * 64 + r0) * K_DIM + cE;
    }
    // LDS dest bases (lane*16 added by HW): + buf*65536 + mat*32768 + p*8192
    char* const dBase = (char*)smem + wave * 1024;

    f32x4 acc[8][4] = {};

    // ---- Prologue: stage tile 0 into buf0: W p0-3, then A p0,p2,p1,p3 ----
    #pragma unroll
    for (int p = 0; p < 4; ++p) GLL(pW[p], dBase + 32768 + p * 8192);
    GLL(pA[0], dBase);
    GLL(pA[2], dBase + 2 * 8192);
    GLL(pA[1], dBase + 1 * 8192);
    GLL(pA[3], dBase + 3 * 8192);
    #pragma unroll
    for (int p = 0; p < 4; ++p) { pA[p] += 64; pW[p] += 64; }
    WAIT_VM(2);        // W all + A{p0,p2} landed; A{p1,p3} in flight
    BARRIER();

    #define MFMA16(AB)                                                         \
        __builtin_amdgcn_s_setprio(1);                                         \
        _Pragma("unroll")                                                      \
        for (int mi = 0; mi < 4; ++mi)                                         \
            _Pragma("unroll")                                                  \
            for (int nj = 0; nj < 4; ++nj)                                     \
                acc[(AB) + mi][nj] = __builtin_amdgcn_mfma_f32_16x16x32_bf16(  \
                    af[mi], bfr[nj], acc[(AB) + mi][nj], 0, 0, 0);             \
        __builtin_amdgcn_s_setprio(0);

    #define TILE_STEP(RB, WB)                                                  \
    {                                                                          \
        const char* sA = (const char*)smem + (RB);                             \
        const char* sW = sA + 32768;                                           \
        bf16x8 bfr[4], af[4];                                                  \
        /* P1: kh0, mh0 */                                                     \
        _Pragma("unroll")                                                      \
        for (int nj = 0; nj < 4; ++nj) bfr[nj] = *(const bf16x8*)(sW + boffB[nj]); \
        _Pragma("unroll")                                                      \
        for (int mi = 0; mi < 4; ++mi) af[mi] = *(const bf16x8*)(sA + aoffB[mi]); \
        _Pragma("unroll")                                                      \
        for (int p = 0; p < 4; ++p) GLL(pW[p], (char*)smem + (WB) + wave * 1024 + 32768 + p * 8192); \
        MFMA16(0)                                                              \
        WAIT_VM(4);   /* A{p1,p3} of current tile landed */                    \
        BARRIER();                                                             \
        /* P2: kh0, mh1 */                                                     \
        _Pragma("unroll")                                                      \
        for (int mi = 0; mi < 4; ++mi) af[mi] = *(const bf16x8*)(sA + aoffB[4 + mi]); \
        GLL(pA[0], (char*)smem + (WB) + wave * 1024);                          \
        GLL(pA[2], (char*)smem + (WB) + wave * 1024 + 2 * 8192);               \
        GLL(pA[1], (char*)smem + (WB) + wave * 1024 + 1 * 8192);               \
        GLL(pA[3], (char*)smem + (WB) + wave * 1024 + 3 * 8192);               \
        MFMA16(4)                                                              \
        /* P3: kh1, mh0 */                                                     \
        _Pragma("unroll")                                                      \
        for (int nj = 0; nj < 4; ++nj) bfr[nj] = *(const bf16x8*)(sW + (boffB[nj] ^ 64)); \
        _Pragma("unroll")                                                      \
        for (int mi = 0; mi < 4; ++mi) af[mi] = *(const bf16x8*)(sA + (aoffB[mi] ^ 64)); \
        MFMA16(0)                                                              \
        /* P4: kh1, mh1 */                                                     \
        _Pragma("unroll")                                                      \
        for (int mi = 0; mi < 4; ++mi) af[mi] = *(const bf16x8*)(sA + (aoffB[4 + mi] ^ 64)); \
        MFMA16(4)                                                              \
        _Pragma("unroll")                                                      \
        for (int p = 0; p < 4; ++p) { pA[p] += 64; pW[p] += 64; }              \
        WAIT_VM(2);   /* next tile: W all + A{p0,p2} landed */                 \
        BARRIER();                                                             \
    }

    for (int it = 0; it < NT / 2; ++it) {
        TILE_STEP(0, 65536)        // even tile: read buf0, stage buf1
        TILE_STEP(65536, 0)        // odd tile:  read buf1, stage buf0
    }
    #undef TILE_STEP
    #undef MFMA16

    // ----- fused LSTM epilogue (lane's 4 n-frags = the 4 gates of one h) -----
    const int hb = (n0 >> 2) + wn * 16 + frow;   // h index for this lane
    float bv[4];
    bv[0] = bW0[hb] + bV0[hb] + bg0[hb];
    bv[1] = bW1[hb] + bV1[hb] + bg1[hb];
    bv[2] = bW2[hb] + bV2[hb] + bg2[hb];
    bv[3] = bW3[hb] + bV3[hb] + bg3[hb];
    const int BH = B_DIM * H_DIM;

    #pragma unroll
    for (int mi = 0; mi < 8; ++mi) {
        int bbase = m0 + wm * 128 + mi * 16 + g * 4;
        #pragma unroll
        for (int r = 0; r < 4; ++r) {
            int b = bbase + r;
            float mk = mask[b];
            float cp = c_prev[(size_t)b * H_DIM + hb];
            float fv = sigf(acc[mi][0][r] + bv[0]);
            float iv = sigf(acc[mi][1][r] + bv[1]);
            float ov = sigf(acc[mi][2][r] + bv[2]);
            float ct = tanf_(acc[mi][3][r] + bv[3]);
            float cn = fv * cp + iv * cp + mk * (iv * ct);
            float hn = ov * tanf_(cn);
            size_t o = (size_t)b * H_DIM + hb;
            out[o]          = hn;
            out[BH + o]     = cn;
            out[2 * BH + o] = ct;
        }
    }
}

// ---------------------------------------------------------------------------
// Launch
// ---------------------------------------------------------------------------
extern "C" void kernel_launch(void* const* d_in, const int* in_sizes, int n_in,
                              void* d_out, int out_size, void* d_ws, size_t ws_size,
                              hipStream_t stream) {
    const float* x      = (const float*)d_in[0];
    const float* h_prev = (const float*)d_in[1];
    const float* c_prev = (const float*)d_in[2];
    const float* Wf = (const float*)d_in[4],  *bWf = (const float*)d_in[5];
    const float* Vf = (const float*)d_in[6],  *bVf = (const float*)d_in[7];
    const float* Wi = (const float*)d_in[8],  *bWi = (const float*)d_in[9];
    const float* Vi = (const float*)d_in[10], *bVi = (const float*)d_in[11];
    const float* Wo = (const float*)d_in[12], *bWo = (const float*)d_in[13];
    const float* Vo = (const float*)d_in[14], *bVo = (const float*)d_in[15];
    const float* Wcg = (const float*)d_in[16], *bWc = (const float*)d_in[17];
    const float* Vc = (const float*)d_in[18], *bVc = (const float*)d_in[19];
    const float* bf = (const float*)d_in[20];
    const float* bi = (const float*)d_in[21];
    const float* bo = (const float*)d_in[22];
    const float* bc = (const float*)d_in[23];

    uint8_t* ws = (uint8_t*)d_ws;
    bf16_t* Abuf  = (bf16_t*)ws;                                   // 16 MiB
    bf16_t* Wbuf  = (bf16_t*)(ws + (size_t)16 * 1024 * 1024);      // 16 MiB
    float*  maskb = (float*)(ws + (size_t)32 * 1024 * 1024);       // 16 KiB

    prep_kernel<<<2 * B_DIM, 256, 0, stream>>>(
        x, h_prev, Wf, Wi, Wo, Wcg, Vf, Vi, Vo, Vc, Abuf, Wbuf, maskb);

    gemm_lstm<<<256, 512, 0, stream>>>(Abuf, Wbuf, c_prev, maskb,
                                       (float*)d_out,
                                       bWf, bWi, bWo, bWc,
                                       bVf, bVi, bVo, bVc,
                                       bf, bi, bo, bc);
}